// Round 5
// baseline (381.788 us; speedup 1.0000x reference)
//
#include <hip/hip_runtime.h>
#include <stdint.h>

typedef uint16_t u16;
typedef __bf16 bf16x8 __attribute__((ext_vector_type(8)));
typedef float f32x4 __attribute__((ext_vector_type(4)));

__device__ __forceinline__ u16 f2bf(float f) {
  union { float f; uint32_t u; } v; v.f = f;
  uint32_t u = v.u;
  u += 0x7FFFu + ((u >> 16) & 1u);   // round-to-nearest-even
  return (u16)(u >> 16);
}
__device__ __forceinline__ float bf2f(u16 h) {
  union { uint32_t u; float f; } v; v.u = ((uint32_t)h) << 16; return v.f;
}

// ---------------------------------------------------------------------------
// Weight transposes (grid.z = 0,1) + LN-fold GEMV (grid.z = 2) in one launch.
// transposes: fp32 [R][C] -> bf16 [C][R]
// gemv: gw2[n] = sum_k gamma[k]*bf16(w2[k][n]); bw2[n] = sum_k beta[k]*...
// (uses bf16-rounded w2 so it matches the MFMA's B operand exactly)
// ---------------------------------------------------------------------------
__global__ void transpose_both(const float* __restrict__ w1, u16* __restrict__ w1t,
                               const float* __restrict__ w2, u16* __restrict__ w2t,
                               const float* __restrict__ gamma,
                               const float* __restrict__ beta,
                               float* __restrict__ gw2, float* __restrict__ bw2) {
  if (blockIdx.z == 2) {
    if (blockIdx.x || blockIdx.y) return;
    int tid = threadIdx.y * 32 + threadIdx.x;
    if (tid < 128) {
      float g = 0.f, b = 0.f;
      for (int k = 0; k < 512; ++k) {
        float w = bf2f(f2bf(w2[(size_t)k * 128 + tid]));
        g += gamma[k] * w; b += beta[k] * w;
      }
      gw2[tid] = g; bw2[tid] = b;
    }
    return;
  }
  const float* in; u16* out; int R, C;
  if (blockIdx.z == 0) { in = w1; out = w1t; R = 1024; C = 512; }
  else {
    if (blockIdx.x >= 4 || blockIdx.y >= 16) return;   // block-uniform exit
    in = w2; out = w2t; R = 512; C = 128;
  }
  __shared__ float tile[32][33];
  int bx = blockIdx.x * 32, by = blockIdx.y * 32;
  int tx = threadIdx.x, ty = threadIdx.y;  // block (32,8)
  for (int i = 0; i < 32; i += 8)
    tile[ty + i][tx] = in[(size_t)(by + ty + i) * C + bx + tx];
  __syncthreads();
  for (int i = 0; i < 32; i += 8)
    out[(size_t)(bx + ty + i) * R + by + tx] = f2bf(tile[tx][ty + i]);
}

// ---------------------------------------------------------------------------
// GEMM1: h = PReLU(x @ w1 + b1)   x fp32 [8192][1024] (cast in staging),
// w1t bf16 [512][1024], out bf16 [8192][512]
// Tile 64x128x64, grid (128,4) = 512 blocks = 2 blocks/CU.
// ---------------------------------------------------------------------------
#define BKT 64

__launch_bounds__(256)
__global__ void gemm1_kernel(const float* __restrict__ A,
                             const u16* __restrict__ Bt,
                             const float* __restrict__ bias,
                             const float* __restrict__ prelu_a,
                             u16* __restrict__ out) {
  const int N = 512, K = 1024;
  __shared__ u16 As[64][BKT + 8];    // 9.2 KB
  __shared__ u16 Bs[128][BKT + 8];   // 18.4 KB
  const int lane = threadIdx.x & 63, wave = threadIdx.x >> 6;
  const int row0 = blockIdx.x * 64, col0 = blockIdx.y * 128;

  f32x4 zero4 = {0.f, 0.f, 0.f, 0.f};
  f32x4 acc[8];
#pragma unroll
  for (int j = 0; j < 8; ++j) acc[j] = zero4;

  for (int k0 = 0; k0 < K; k0 += BKT) {
#pragma unroll
    for (int s = 0; s < 2; ++s) {
      int c = threadIdx.x + s * 256;
      int r = c >> 3, kc = (c & 7) << 3;
      const float4* p = (const float4*)(A + (size_t)(row0 + r) * K + k0 + kc);
      float4 f0 = p[0], f1 = p[1];
      u16 tmp[8] = {f2bf(f0.x), f2bf(f0.y), f2bf(f0.z), f2bf(f0.w),
                    f2bf(f1.x), f2bf(f1.y), f2bf(f1.z), f2bf(f1.w)};
      *(uint4*)(&As[r][kc]) = *(uint4*)tmp;
    }
#pragma unroll
    for (int s = 0; s < 4; ++s) {
      int c = threadIdx.x + s * 256;
      int r = c >> 3, kc = (c & 7) << 3;
      *(uint4*)(&Bs[r][kc]) = *(const uint4*)(Bt + (size_t)(col0 + r) * K + k0 + kc);
    }
    __syncthreads();
#pragma unroll
    for (int kk = 0; kk < BKT; kk += 32) {
      bf16x8 a, b[8];
      a = *(const bf16x8*)(&As[wave * 16 + (lane & 15)][kk + (lane >> 4) * 8]);
#pragma unroll
      for (int j = 0; j < 8; ++j)
        b[j] = *(const bf16x8*)(&Bs[j * 16 + (lane & 15)][kk + (lane >> 4) * 8]);
#pragma unroll
      for (int j = 0; j < 8; ++j)
        acc[j] = __builtin_amdgcn_mfma_f32_16x16x32_bf16(a, b[j], acc[j], 0, 0, 0);
    }
    __syncthreads();
  }

  float ap = *prelu_a;
#pragma unroll
  for (int r = 0; r < 4; ++r) {
    int row = row0 + wave * 16 + (lane >> 4) * 4 + r;
#pragma unroll
    for (int j = 0; j < 8; ++j) {
      int col = col0 + j * 16 + (lane & 15);
      float v = acc[j][r] + bias[col];
      v = v >= 0.f ? v : ap * v;
      out[(size_t)row * N + col] = f2bf(v);
    }
  }
}

// ---------------------------------------------------------------------------
// GEMM2 with LN folded in + bias + row-normalize.
//   hln = (hact-mu)*rstd*gamma + beta   (per-row mu,rstd)
//   z   = hln@w2 + b2 = rstd*((hact*gamma)@w2) - mu*rstd*gw2 + bw2 + b2
// A-staging multiplies gamma in (bf16), and accumulates per-row sum/sumsq of
// the RAW hact values (each element staged exactly once by a fixed thread).
// BM=32, grid 256, 4 waves in 2x2 split (R4 geometry).
// ---------------------------------------------------------------------------
__launch_bounds__(256)
__global__ void gemm2_kernel(const u16* __restrict__ A, const u16* __restrict__ Bt,
                             const float* __restrict__ b2,
                             const float* __restrict__ gamma,
                             const float* __restrict__ gw2,
                             const float* __restrict__ bw2,
                             float* __restrict__ z, u16* __restrict__ zn) {
  const int K = 512;
  __shared__ u16 As[32][BKT + 8];    // 4.6 KB
  __shared__ u16 Bs[128][BKT + 8];   // 18.4 KB
  __shared__ float rs[32][8], rs2[32][8];   // per-(row, k-chunk-thread) partials
  __shared__ float mu_s[32], rstd_s[32];
  __shared__ float hsum[32][2];      // per-row half sums of ||z||^2
  const int lane = threadIdx.x & 63, wave = threadIdx.x >> 6;
  const int wr = wave >> 1, wc = wave & 1;
  const int row0 = blockIdx.x * 32;

  f32x4 zero4 = {0.f, 0.f, 0.f, 0.f};
  f32x4 acc[4];
#pragma unroll
  for (int j = 0; j < 4; ++j) acc[j] = zero4;

  const int ar = threadIdx.x >> 3, akc = (threadIdx.x & 7) << 3;
  float sp = 0.f, sp2 = 0.f;   // private stats partials (row ar, chunks akc)

  for (int k0 = 0; k0 < K; k0 += BKT) {
    {  // A panel: 32 rows, 1 chunk/thread; gamma-scale + stats
      uint4 raw = *(const uint4*)(A + (size_t)(row0 + ar) * K + k0 + akc);
      u16* up = (u16*)&raw;
      u16 tmp[8];
#pragma unroll
      for (int e = 0; e < 8; ++e) {
        float v = bf2f(up[e]);
        sp += v; sp2 += v * v;
        tmp[e] = f2bf(v * gamma[k0 + akc + e]);
      }
      *(uint4*)(&As[ar][akc]) = *(uint4*)tmp;
    }
#pragma unroll
    for (int s = 0; s < 4; ++s) {   // B panel: 128 rows
      int c = threadIdx.x + s * 256;
      int r = c >> 3, kc = (c & 7) << 3;
      *(uint4*)(&Bs[r][kc]) = *(const uint4*)(Bt + (size_t)r * K + k0 + kc);
    }
    __syncthreads();
#pragma unroll
    for (int kk = 0; kk < BKT; kk += 32) {
      bf16x8 a, b[4];
      a = *(const bf16x8*)(&As[wr * 16 + (lane & 15)][kk + (lane >> 4) * 8]);
#pragma unroll
      for (int j = 0; j < 4; ++j)
        b[j] = *(const bf16x8*)(&Bs[wc * 64 + j * 16 + (lane & 15)][kk + (lane >> 4) * 8]);
#pragma unroll
      for (int j = 0; j < 4; ++j)
        acc[j] = __builtin_amdgcn_mfma_f32_16x16x32_bf16(a, b[j], acc[j], 0, 0, 0);
    }
    __syncthreads();
  }

  // finalize per-row LN stats: 8 staging threads per row -> LDS reduce
  rs[ar][threadIdx.x & 7] = sp;
  rs2[ar][threadIdx.x & 7] = sp2;
  __syncthreads();
  if (threadIdx.x < 32) {
    float S = 0.f, Q = 0.f;
#pragma unroll
    for (int t = 0; t < 8; ++t) { S += rs[threadIdx.x][t]; Q += rs2[threadIdx.x][t]; }
    float mu = S * (1.f / 512.f);
    float var = Q * (1.f / 512.f) - mu * mu;
    mu_s[threadIdx.x] = mu;
    rstd_s[threadIdx.x] = rsqrtf(var + 1e-6f);
  }
  __syncthreads();

  // epilogue: LN correction + b2, half-row sumsq, exchange, normalize, store
  float vv[4][4];   // [r][j]
#pragma unroll
  for (int r = 0; r < 4; ++r) {
    int rloc = wr * 16 + (lane >> 4) * 4 + r;
    float mu = mu_s[rloc], rstd = rstd_s[rloc];
    float s = 0.f;
#pragma unroll
    for (int j = 0; j < 4; ++j) {
      int col = wc * 64 + j * 16 + (lane & 15);
      float v = rstd * acc[j][r] - mu * rstd * gw2[col] + bw2[col] + b2[col];
      vv[r][j] = v; s += v * v;
    }
    s += __shfl_xor(s, 1); s += __shfl_xor(s, 2);
    s += __shfl_xor(s, 4); s += __shfl_xor(s, 8);
    if ((lane & 15) == 0) hsum[rloc][wc] = s;
  }
  __syncthreads();
#pragma unroll
  for (int r = 0; r < 4; ++r) {
    int rloc = wr * 16 + (lane >> 4) * 4 + r;
    float s = hsum[rloc][0] + hsum[rloc][1];
    float inv = 1.f / fmaxf(sqrtf(s), 1e-8f);
    int row = row0 + rloc;
#pragma unroll
    for (int j = 0; j < 4; ++j) {
      int col = wc * 64 + j * 16 + (lane & 15);
      z[(size_t)row * 128 + col] = vv[r][j];
      zn[(size_t)row * 128 + col] = f2bf(vv[r][j] * inv);
    }
  }
}

// ---------------------------------------------------------------------------
// Gram: y = zn @ zn^T, zn bf16 [8192][128], y fp32 [8192][8192].
// Round-0 form: double-staged k0 loop, 36.9 KB LDS (4 blocks/CU), normal
// stores. (NT stores + single-stage 69.6 KB were a +19 us regression.)
// ---------------------------------------------------------------------------
#define GBM 128
#define GBN 128

__launch_bounds__(256)
__global__ void gram_kernel(const u16* __restrict__ Z, float* __restrict__ y) {
  const int K = 128, Bdim = 8192;
  __shared__ u16 As[GBM][BKT + 8];
  __shared__ u16 Bs[GBN][BKT + 8];
  const int lane = threadIdx.x & 63, wave = threadIdx.x >> 6;
  const int row0 = blockIdx.x * GBM, col0 = blockIdx.y * GBN;

  f32x4 zero4 = {0.f, 0.f, 0.f, 0.f};
  f32x4 acc[2][8];
#pragma unroll
  for (int i = 0; i < 2; ++i)
#pragma unroll
    for (int j = 0; j < 8; ++j) acc[i][j] = zero4;

  for (int k0 = 0; k0 < K; k0 += BKT) {
#pragma unroll
    for (int s = 0; s < 4; ++s) {
      int c = threadIdx.x + s * 256;
      int r = c >> 3, kc = (c & 7) << 3;
      *(uint4*)(&As[r][kc]) = *(const uint4*)(Z + (size_t)(row0 + r) * K + k0 + kc);
      *(uint4*)(&Bs[r][kc]) = *(const uint4*)(Z + (size_t)(col0 + r) * K + k0 + kc);
    }
    __syncthreads();
#pragma unroll
    for (int kk = 0; kk < BKT; kk += 32) {
      bf16x8 a[2], b[8];
#pragma unroll
      for (int i = 0; i < 2; ++i)
        a[i] = *(const bf16x8*)(&As[wave * 32 + i * 16 + (lane & 15)][kk + (lane >> 4) * 8]);
#pragma unroll
      for (int j = 0; j < 8; ++j)
        b[j] = *(const bf16x8*)(&Bs[j * 16 + (lane & 15)][kk + (lane >> 4) * 8]);
#pragma unroll
      for (int i = 0; i < 2; ++i)
#pragma unroll
        for (int j = 0; j < 8; ++j)
          acc[i][j] = __builtin_amdgcn_mfma_f32_16x16x32_bf16(a[i], b[j], acc[i][j], 0, 0, 0);
    }
    __syncthreads();
  }

#pragma unroll
  for (int i = 0; i < 2; ++i)
#pragma unroll
    for (int r = 0; r < 4; ++r) {
      int row = row0 + wave * 32 + i * 16 + (lane >> 4) * 4 + r;
#pragma unroll
      for (int j = 0; j < 8; ++j) {
        int col = col0 + j * 16 + (lane & 15);
        y[(size_t)row * Bdim + col] = acc[i][j][r];
      }
    }
}

// ---------------------------------------------------------------------------
// Launch. Inputs: x, w1, b1, prelu_a, ln_gamma, ln_beta, w2, b2.
// d_out = [z (8192*128) | y_hat (8192*8192)] fp32.
// ws (bytes): w1t 1 MB @0, w2t 128 KB, hact 8 MB, zn 2 MB, gw2/bw2 512 B ea.
// ---------------------------------------------------------------------------
extern "C" void kernel_launch(void* const* d_in, const int* in_sizes, int n_in,
                              void* d_out, int out_size, void* d_ws, size_t ws_size,
                              hipStream_t stream) {
  const float* x       = (const float*)d_in[0];
  const float* w1      = (const float*)d_in[1];
  const float* b1      = (const float*)d_in[2];
  const float* prelu_a = (const float*)d_in[3];
  const float* gamma   = (const float*)d_in[4];
  const float* beta    = (const float*)d_in[5];
  const float* w2      = (const float*)d_in[6];
  const float* b2      = (const float*)d_in[7];

  float* z_out = (float*)d_out;
  float* yhat  = z_out + (size_t)8192 * 128;

  char* ws = (char*)d_ws;
  u16* w1t  = (u16*)(ws);                                        // [512][1024]  1 MB
  u16* w2t  = (u16*)(ws + (1u << 20));                           // [128][512]   128 KB
  u16* hact = (u16*)(ws + (1u << 20) + (1u << 17));              // [8192][512]  8 MB
  u16* zn   = (u16*)(ws + (1u << 20) + (1u << 17) + (8u << 20)); // [8192][128]  2 MB
  float* gw2 = (float*)(ws + (1u << 20) + (1u << 17) + (10u << 20));        // [128]
  float* bw2 = (float*)(ws + (1u << 20) + (1u << 17) + (10u << 20) + 512);  // [128]

  transpose_both<<<dim3(16, 32, 3), dim3(32, 8), 0, stream>>>(
      w1, w1t, w2, w2t, gamma, beta, gw2, bw2);
  gemm1_kernel<<<dim3(128, 4), 256, 0, stream>>>(x, w1t, b1, prelu_a, hact);
  gemm2_kernel<<<256, 256, 0, stream>>>(hact, w2t, b2, gamma, gw2, bw2, z_out, zn);
  gram_kernel<<<dim3(64, 64), 256, 0, stream>>>(zn, yhat);
}

// Round 6
// 347.384 us; speedup vs baseline: 1.0990x; 1.0990x over previous
//
#include <hip/hip_runtime.h>
#include <stdint.h>

typedef uint16_t u16;
typedef __bf16 bf16x8 __attribute__((ext_vector_type(8)));
typedef float f32x4 __attribute__((ext_vector_type(4)));

__device__ __forceinline__ u16 f2bf(float f) {
  union { float f; uint32_t u; } v; v.f = f;
  uint32_t u = v.u;
  u += 0x7FFFu + ((u >> 16) & 1u);   // round-to-nearest-even
  return (u16)(u >> 16);
}
__device__ __forceinline__ float bf2f(u16 h) {
  union { uint32_t u; float f; } v; v.u = ((uint32_t)h) << 16; return v.f;
}

// ---------------------------------------------------------------------------
// Both weight transposes in one launch (grid.z selects matrix).
// fp32 [R][C] -> bf16 [C][R]
// ---------------------------------------------------------------------------
__global__ void transpose_both(const float* __restrict__ w1, u16* __restrict__ w1t,
                               const float* __restrict__ w2, u16* __restrict__ w2t) {
  const float* in; u16* out; int R, C;
  if (blockIdx.z == 0) { in = w1; out = w1t; R = 1024; C = 512; }
  else {
    if (blockIdx.x >= 4 || blockIdx.y >= 16) return;   // block-uniform exit
    in = w2; out = w2t; R = 512; C = 128;
  }
  __shared__ float tile[32][33];
  int bx = blockIdx.x * 32, by = blockIdx.y * 32;
  int tx = threadIdx.x, ty = threadIdx.y;  // block (32,8)
  for (int i = 0; i < 32; i += 8)
    tile[ty + i][tx] = in[(size_t)(by + ty + i) * C + bx + tx];
  __syncthreads();
  for (int i = 0; i < 32; i += 8)
    out[(size_t)(bx + ty + i) * R + by + tx] = f2bf(tile[tx][ty + i]);
}

// ---------------------------------------------------------------------------
// GEMM1: h = PReLU(x @ w1 + b1)   x fp32 [8192][1024] (cast in staging),
// w1t bf16 [512][1024], out bf16 [8192][512]
// Tile 64x128x64, grid (128,5): by<4 = 512 GEMM blocks (2 blocks/CU);
// by==4 = 128 GEMV blocks computing gw2[n]=gamma@bf16(w2[:,n]),
// bw2[n]=beta@bf16(w2[:,n]) — one block per column, reading the contiguous
// w2t row.  (R5 ran this GEMV as ONE serial block: ~+19 us chain stall.)
// ---------------------------------------------------------------------------
#define BKT 64

__launch_bounds__(256)
__global__ void gemm1_kernel(const float* __restrict__ A,
                             const u16* __restrict__ Bt,
                             const float* __restrict__ bias,
                             const float* __restrict__ prelu_a,
                             u16* __restrict__ out,
                             const u16* __restrict__ w2t,
                             const float* __restrict__ gamma,
                             const float* __restrict__ beta,
                             float* __restrict__ gw2, float* __restrict__ bw2) {
  const int N = 512, K = 1024;
  __shared__ u16 As[64][BKT + 8];    // 9.2 KB
  __shared__ u16 Bs[128][BKT + 8];   // 18.4 KB
  const int lane = threadIdx.x & 63, wave = threadIdx.x >> 6;

  if (blockIdx.y == 4) {
    // ---- parallel LN-fold GEMV: this block owns output column `col` ----
    __shared__ float gg[4], bb[4];
    int col = blockIdx.x;
    float g = 0.f, b = 0.f;
#pragma unroll
    for (int s = 0; s < 2; ++s) {
      int k = threadIdx.x + s * 256;
      float w = bf2f(w2t[(size_t)col * 512 + k]);
      g += gamma[k] * w; b += beta[k] * w;
    }
    for (int m = 1; m < 64; m <<= 1) { g += __shfl_xor(g, m); b += __shfl_xor(b, m); }
    if (lane == 0) { gg[wave] = g; bb[wave] = b; }
    __syncthreads();
    if (threadIdx.x == 0) {
      gw2[col] = gg[0] + gg[1] + gg[2] + gg[3];
      bw2[col] = bb[0] + bb[1] + bb[2] + bb[3];
    }
    return;
  }

  const int row0 = blockIdx.x * 64, col0 = blockIdx.y * 128;

  f32x4 zero4 = {0.f, 0.f, 0.f, 0.f};
  f32x4 acc[8];
#pragma unroll
  for (int j = 0; j < 8; ++j) acc[j] = zero4;

  for (int k0 = 0; k0 < K; k0 += BKT) {
#pragma unroll
    for (int s = 0; s < 2; ++s) {
      int c = threadIdx.x + s * 256;
      int r = c >> 3, kc = (c & 7) << 3;
      const float4* p = (const float4*)(A + (size_t)(row0 + r) * K + k0 + kc);
      float4 f0 = p[0], f1 = p[1];
      u16 tmp[8] = {f2bf(f0.x), f2bf(f0.y), f2bf(f0.z), f2bf(f0.w),
                    f2bf(f1.x), f2bf(f1.y), f2bf(f1.z), f2bf(f1.w)};
      *(uint4*)(&As[r][kc]) = *(uint4*)tmp;
    }
#pragma unroll
    for (int s = 0; s < 4; ++s) {
      int c = threadIdx.x + s * 256;
      int r = c >> 3, kc = (c & 7) << 3;
      *(uint4*)(&Bs[r][kc]) = *(const uint4*)(Bt + (size_t)(col0 + r) * K + k0 + kc);
    }
    __syncthreads();
#pragma unroll
    for (int kk = 0; kk < BKT; kk += 32) {
      bf16x8 a, b[8];
      a = *(const bf16x8*)(&As[wave * 16 + (lane & 15)][kk + (lane >> 4) * 8]);
#pragma unroll
      for (int j = 0; j < 8; ++j)
        b[j] = *(const bf16x8*)(&Bs[j * 16 + (lane & 15)][kk + (lane >> 4) * 8]);
#pragma unroll
      for (int j = 0; j < 8; ++j)
        acc[j] = __builtin_amdgcn_mfma_f32_16x16x32_bf16(a, b[j], acc[j], 0, 0, 0);
    }
    __syncthreads();
  }

  float ap = *prelu_a;
#pragma unroll
  for (int r = 0; r < 4; ++r) {
    int row = row0 + wave * 16 + (lane >> 4) * 4 + r;
#pragma unroll
    for (int j = 0; j < 8; ++j) {
      int col = col0 + j * 16 + (lane & 15);
      float v = acc[j][r] + bias[col];
      v = v >= 0.f ? v : ap * v;
      out[(size_t)row * N + col] = f2bf(v);
    }
  }
}

// ---------------------------------------------------------------------------
// GEMM2 with LN folded in + bias + row-normalize.
//   hln = (hact-mu)*rstd*gamma + beta   (per-row mu,rstd)
//   z   = hln@w2 + b2 = rstd*((hact*gamma)@w2) - mu*rstd*gw2 + bw2 + b2
// A-staging multiplies gamma (from LDS cache) and accumulates per-row
// sum/sumsq of raw hact (each element staged exactly once by a fixed thread).
// BM=32, grid 256, 4 waves in 2x2 split.
// ---------------------------------------------------------------------------
__launch_bounds__(256)
__global__ void gemm2_kernel(const u16* __restrict__ A, const u16* __restrict__ Bt,
                             const float* __restrict__ b2,
                             const float* __restrict__ gamma,
                             const float* __restrict__ gw2,
                             const float* __restrict__ bw2,
                             float* __restrict__ z, u16* __restrict__ zn) {
  const int K = 512;
  __shared__ u16 As[32][BKT + 8];    // 4.6 KB
  __shared__ u16 Bs[128][BKT + 8];   // 18.4 KB
  __shared__ float gs[512];          // gamma cache, 2 KB
  __shared__ float rs[32][8], rs2[32][8];
  __shared__ float mu_s[32], rstd_s[32];
  __shared__ float hsum[32][2];
  const int lane = threadIdx.x & 63, wave = threadIdx.x >> 6;
  const int wr = wave >> 1, wc = wave & 1;
  const int row0 = blockIdx.x * 32;

  gs[threadIdx.x] = gamma[threadIdx.x];
  gs[threadIdx.x + 256] = gamma[threadIdx.x + 256];
  __syncthreads();

  f32x4 zero4 = {0.f, 0.f, 0.f, 0.f};
  f32x4 acc[4];
#pragma unroll
  for (int j = 0; j < 4; ++j) acc[j] = zero4;

  const int ar = threadIdx.x >> 3, akc = (threadIdx.x & 7) << 3;
  float sp = 0.f, sp2 = 0.f;   // private stats partials (row ar, chunk akc)

  for (int k0 = 0; k0 < K; k0 += BKT) {
    {  // A panel: 32 rows, 1 chunk/thread; gamma-scale + stats
      uint4 raw = *(const uint4*)(A + (size_t)(row0 + ar) * K + k0 + akc);
      u16* up = (u16*)&raw;
      u16 tmp[8];
#pragma unroll
      for (int e = 0; e < 8; ++e) {
        float v = bf2f(up[e]);
        sp += v; sp2 += v * v;
        tmp[e] = f2bf(v * gs[k0 + akc + e]);
      }
      *(uint4*)(&As[ar][akc]) = *(uint4*)tmp;
    }
#pragma unroll
    for (int s = 0; s < 4; ++s) {   // B panel: 128 rows
      int c = threadIdx.x + s * 256;
      int r = c >> 3, kc = (c & 7) << 3;
      *(uint4*)(&Bs[r][kc]) = *(const uint4*)(Bt + (size_t)r * K + k0 + kc);
    }
    __syncthreads();
#pragma unroll
    for (int kk = 0; kk < BKT; kk += 32) {
      bf16x8 a, b[4];
      a = *(const bf16x8*)(&As[wr * 16 + (lane & 15)][kk + (lane >> 4) * 8]);
#pragma unroll
      for (int j = 0; j < 4; ++j)
        b[j] = *(const bf16x8*)(&Bs[wc * 64 + j * 16 + (lane & 15)][kk + (lane >> 4) * 8]);
#pragma unroll
      for (int j = 0; j < 4; ++j)
        acc[j] = __builtin_amdgcn_mfma_f32_16x16x32_bf16(a, b[j], acc[j], 0, 0, 0);
    }
    __syncthreads();
  }

  // finalize per-row LN stats: 8 staging threads per row -> LDS reduce
  rs[ar][threadIdx.x & 7] = sp;
  rs2[ar][threadIdx.x & 7] = sp2;
  __syncthreads();
  if (threadIdx.x < 32) {
    float S = 0.f, Q = 0.f;
#pragma unroll
    for (int t = 0; t < 8; ++t) { S += rs[threadIdx.x][t]; Q += rs2[threadIdx.x][t]; }
    float mu = S * (1.f / 512.f);
    float var = Q * (1.f / 512.f) - mu * mu;
    mu_s[threadIdx.x] = mu;
    rstd_s[threadIdx.x] = rsqrtf(var + 1e-6f);
  }
  __syncthreads();

  // epilogue: LN correction + b2, half-row sumsq, exchange, normalize, store
  float vv[4][4];   // [r][j]
#pragma unroll
  for (int r = 0; r < 4; ++r) {
    int rloc = wr * 16 + (lane >> 4) * 4 + r;
    float mu = mu_s[rloc], rstd = rstd_s[rloc];
    float s = 0.f;
#pragma unroll
    for (int j = 0; j < 4; ++j) {
      int col = wc * 64 + j * 16 + (lane & 15);
      float v = rstd * acc[j][r] - mu * rstd * gw2[col] + bw2[col] + b2[col];
      vv[r][j] = v; s += v * v;
    }
    s += __shfl_xor(s, 1); s += __shfl_xor(s, 2);
    s += __shfl_xor(s, 4); s += __shfl_xor(s, 8);
    if ((lane & 15) == 0) hsum[rloc][wc] = s;
  }
  __syncthreads();
#pragma unroll
  for (int r = 0; r < 4; ++r) {
    int rloc = wr * 16 + (lane >> 4) * 4 + r;
    float s = hsum[rloc][0] + hsum[rloc][1];
    float inv = 1.f / fmaxf(sqrtf(s), 1e-8f);
    int row = row0 + rloc;
#pragma unroll
    for (int j = 0; j < 4; ++j) {
      int col = wc * 64 + j * 16 + (lane & 15);
      z[(size_t)row * 128 + col] = vv[r][j];
      zn[(size_t)row * 128 + col] = f2bf(vv[r][j] * inv);
    }
  }
}

// ---------------------------------------------------------------------------
// Gram: y = zn @ zn^T, zn bf16 [8192][128], y fp32 [8192][8192].
// Round-0 form: double-staged k0 loop, 36.9 KB LDS (4 blocks/CU), normal
// stores. (NT stores + single-stage 69.6 KB were a +19 us regression.)
// ---------------------------------------------------------------------------
#define GBM 128
#define GBN 128

__launch_bounds__(256)
__global__ void gram_kernel(const u16* __restrict__ Z, float* __restrict__ y) {
  const int K = 128, Bdim = 8192;
  __shared__ u16 As[GBM][BKT + 8];
  __shared__ u16 Bs[GBN][BKT + 8];
  const int lane = threadIdx.x & 63, wave = threadIdx.x >> 6;
  const int row0 = blockIdx.x * GBM, col0 = blockIdx.y * GBN;

  f32x4 zero4 = {0.f, 0.f, 0.f, 0.f};
  f32x4 acc[2][8];
#pragma unroll
  for (int i = 0; i < 2; ++i)
#pragma unroll
    for (int j = 0; j < 8; ++j) acc[i][j] = zero4;

  for (int k0 = 0; k0 < K; k0 += BKT) {
#pragma unroll
    for (int s = 0; s < 4; ++s) {
      int c = threadIdx.x + s * 256;
      int r = c >> 3, kc = (c & 7) << 3;
      *(uint4*)(&As[r][kc]) = *(const uint4*)(Z + (size_t)(row0 + r) * K + k0 + kc);
      *(uint4*)(&Bs[r][kc]) = *(const uint4*)(Z + (size_t)(col0 + r) * K + k0 + kc);
    }
    __syncthreads();
#pragma unroll
    for (int kk = 0; kk < BKT; kk += 32) {
      bf16x8 a[2], b[8];
#pragma unroll
      for (int i = 0; i < 2; ++i)
        a[i] = *(const bf16x8*)(&As[wave * 32 + i * 16 + (lane & 15)][kk + (lane >> 4) * 8]);
#pragma unroll
      for (int j = 0; j < 8; ++j)
        b[j] = *(const bf16x8*)(&Bs[j * 16 + (lane & 15)][kk + (lane >> 4) * 8]);
#pragma unroll
      for (int i = 0; i < 2; ++i)
#pragma unroll
        for (int j = 0; j < 8; ++j)
          acc[i][j] = __builtin_amdgcn_mfma_f32_16x16x32_bf16(a[i], b[j], acc[i][j], 0, 0, 0);
    }
    __syncthreads();
  }

#pragma unroll
  for (int i = 0; i < 2; ++i)
#pragma unroll
    for (int r = 0; r < 4; ++r) {
      int row = row0 + wave * 32 + i * 16 + (lane >> 4) * 4 + r;
#pragma unroll
      for (int j = 0; j < 8; ++j) {
        int col = col0 + j * 16 + (lane & 15);
        y[(size_t)row * Bdim + col] = acc[i][j][r];
      }
    }
}

// ---------------------------------------------------------------------------
// Launch. Inputs: x, w1, b1, prelu_a, ln_gamma, ln_beta, w2, b2.
// d_out = [z (8192*128) | y_hat (8192*8192)] fp32.
// ws (bytes): w1t 1 MB @0, w2t 128 KB, hact 8 MB, zn 2 MB, gw2/bw2 512 B ea.
// ---------------------------------------------------------------------------
extern "C" void kernel_launch(void* const* d_in, const int* in_sizes, int n_in,
                              void* d_out, int out_size, void* d_ws, size_t ws_size,
                              hipStream_t stream) {
  const float* x       = (const float*)d_in[0];
  const float* w1      = (const float*)d_in[1];
  const float* b1      = (const float*)d_in[2];
  const float* prelu_a = (const float*)d_in[3];
  const float* gamma   = (const float*)d_in[4];
  const float* beta    = (const float*)d_in[5];
  const float* w2      = (const float*)d_in[6];
  const float* b2      = (const float*)d_in[7];

  float* z_out = (float*)d_out;
  float* yhat  = z_out + (size_t)8192 * 128;

  char* ws = (char*)d_ws;
  u16* w1t  = (u16*)(ws);                                        // [512][1024]  1 MB
  u16* w2t  = (u16*)(ws + (1u << 20));                           // [128][512]   128 KB
  u16* hact = (u16*)(ws + (1u << 20) + (1u << 17));              // [8192][512]  8 MB
  u16* zn   = (u16*)(ws + (1u << 20) + (1u << 17) + (8u << 20)); // [8192][128]  2 MB
  float* gw2 = (float*)(ws + (1u << 20) + (1u << 17) + (10u << 20));        // [128]
  float* bw2 = (float*)(ws + (1u << 20) + (1u << 17) + (10u << 20) + 512);  // [128]

  transpose_both<<<dim3(16, 32, 2), dim3(32, 8), 0, stream>>>(w1, w1t, w2, w2t);
  gemm1_kernel<<<dim3(128, 5), 256, 0, stream>>>(x, w1t, b1, prelu_a, hact,
                                                 w2t, gamma, beta, gw2, bw2);
  gemm2_kernel<<<256, 256, 0, stream>>>(hact, w2t, b2, gamma, gw2, bw2, z_out, zn);
  gram_kernel<<<dim3(64, 64), 256, 0, stream>>>(zn, yhat);
}